// Round 1
// baseline (486.118 us; speedup 1.0000x reference)
//
#include <hip/hip_runtime.h>
#include <math.h>

#define N_NODES 50000
#define N_EDGES 800000
#define N_CAND  100000
#define D       128
#define BN_EPS  1e-5f
#define SLOPE   0.01f

__device__ __forceinline__ float lrelu(float x){ return x >= 0.f ? x : SLOPE * x; }

// ---------------- CSR build ----------------
__global__ __launch_bounds__(256) void k_hist(const int* __restrict__ dst, int* __restrict__ cnt, int E){
  int i = blockIdx.x * 256 + threadIdx.x;
  if (i < E) atomicAdd(&cnt[dst[i]], 1);
}

__global__ __launch_bounds__(256) void k_scan1(const int* __restrict__ cnt, int* __restrict__ rowptr,
                                               int* __restrict__ bsum, int n){
  __shared__ int sd[256];
  int t = threadIdx.x; int i = blockIdx.x * 256 + t;
  int v = (i < n) ? cnt[i] : 0;
  sd[t] = v; __syncthreads();
  for (int off = 1; off < 256; off <<= 1){
    int add = (t >= off) ? sd[t - off] : 0;
    __syncthreads();
    sd[t] += add; __syncthreads();
  }
  if (i < n) rowptr[i] = sd[t] - v;          // exclusive within block
  if (t == 255) bsum[blockIdx.x] = sd[255];  // block total
}

__global__ __launch_bounds__(256) void k_scan2(int* __restrict__ bsum, int* __restrict__ rowptr, int nb, int n){
  __shared__ int sd[256];
  int t = threadIdx.x;
  int v = (t < nb) ? bsum[t] : 0;
  sd[t] = v; __syncthreads();
  for (int off = 1; off < 256; off <<= 1){
    int add = (t >= off) ? sd[t - off] : 0;
    __syncthreads();
    sd[t] += add; __syncthreads();
  }
  if (t < nb) bsum[t] = sd[t] - v;           // exclusive block offsets
  if (t == nb - 1) rowptr[n] = sd[t];        // total = E
}

__global__ __launch_bounds__(256) void k_scan3(int* __restrict__ rowptr, const int* __restrict__ bsum, int n){
  int i = blockIdx.x * 256 + threadIdx.x;
  if (i < n) rowptr[i] += bsum[blockIdx.x];
}

__global__ __launch_bounds__(256) void k_fill(const int* __restrict__ src, const int* __restrict__ dst,
                                              const int* __restrict__ rowptr, int* __restrict__ cur,
                                              int* __restrict__ eid, int E){
  int i = blockIdx.x * 256 + threadIdx.x;
  if (i < E){
    int d = dst[i];
    int p = atomicAdd(&cur[d], 1);
    eid[rowptr[d] + p] = src[i];
  }
}

// ---------------- mean aggregation (gather-sum over CSR) ----------------
__global__ __launch_bounds__(256) void k_agg(const float* __restrict__ X, const int* __restrict__ rowptr,
                                             const int* __restrict__ eid, float* __restrict__ AG, int n){
  int g = blockIdx.x * 8 + (threadIdx.x >> 5);   // node, 32 lanes per node
  int l = threadIdx.x & 31;                      // float4 chunk
  if (g >= n) return;
  int e0 = rowptr[g], e1 = rowptr[g + 1];
  float4 acc = make_float4(0.f, 0.f, 0.f, 0.f);
  for (int e = e0; e < e1; ++e){
    int s = eid[e];
    const float4 v = *reinterpret_cast<const float4*>(&X[(size_t)s * D + l * 4]);
    acc.x += v.x; acc.y += v.y; acc.z += v.z; acc.w += v.w;
  }
  float sc = 1.f / fmaxf((float)(e1 - e0), 1.f);
  acc.x *= sc; acc.y *= sc; acc.z *= sc; acc.w *= sc;
  *reinterpret_cast<float4*>(&AG[(size_t)g * D + l * 4]) = acc;
}

// ---------------- SAGE layer: H = lrelu(BN(X@WS + AG@WN + B)) ----------------
// 32 nodes/block, 256 threads, 4x4 microtile per thread.
__global__ __launch_bounds__(256) void k_sage(const float* __restrict__ X, const float* __restrict__ AG,
    const float* __restrict__ WS, const float* __restrict__ WN,
    const float* __restrict__ B,  const float* __restrict__ GM, const float* __restrict__ BT,
    const float* __restrict__ RM, const float* __restrict__ RV,
    float* __restrict__ H, int n, int donan)
{
  __shared__ float xs[D][36];   // transposed A tiles, pad 36 keeps 16B alignment, conflict-light
  __shared__ float as_[D][36];
  int t = threadIdx.x;
  int node0 = blockIdx.x * 32;
  {
    int row = t >> 3;    // 0..31 node in tile
    int cb  = t & 7;     // float4 column base
    for (int c4 = cb; c4 < 32; c4 += 8){
      int node = node0 + row;
      float4 v = make_float4(0.f,0.f,0.f,0.f), a = make_float4(0.f,0.f,0.f,0.f);
      if (node < n){
        v = *reinterpret_cast<const float4*>(&X [(size_t)node * D + c4 * 4]);
        a = *reinterpret_cast<const float4*>(&AG[(size_t)node * D + c4 * 4]);
      }
      xs [c4*4+0][row] = v.x; xs [c4*4+1][row] = v.y; xs [c4*4+2][row] = v.z; xs [c4*4+3][row] = v.w;
      as_[c4*4+0][row] = a.x; as_[c4*4+1][row] = a.y; as_[c4*4+2][row] = a.z; as_[c4*4+3][row] = a.w;
    }
  }
  __syncthreads();

  int tcol = t & 31, trow = t >> 5;   // trow 0..7 -> nodes trow*4..+3 ; tcol -> cols tcol*4..+3
  float acc[4][4] = {};
  #pragma unroll 2
  for (int k = 0; k < D; ++k){
    float4 av = *reinterpret_cast<const float4*>(&xs [k][trow * 4]);
    float4 gv = *reinterpret_cast<const float4*>(&as_[k][trow * 4]);
    float4 ws = *reinterpret_cast<const float4*>(&WS[k * D + tcol * 4]);
    float4 wn = *reinterpret_cast<const float4*>(&WN[k * D + tcol * 4]);
    const float* ap = (const float*)&av; const float* gp = (const float*)&gv;
    const float* wp = (const float*)&ws; const float* np = (const float*)&wn;
    #pragma unroll
    for (int m = 0; m < 4; ++m){
      #pragma unroll
      for (int j = 0; j < 4; ++j)
        acc[m][j] = fmaf(ap[m], wp[j], fmaf(gp[m], np[j], acc[m][j]));
    }
  }

  // epilogue: fold bias + BN, then leaky relu (+ nan_to_num for layer 2)
  float sj[4], cj[4];
  #pragma unroll
  for (int j = 0; j < 4; ++j){
    int col = tcol * 4 + j;
    float s = GM[col] * rsqrtf(RV[col] + BN_EPS);
    sj[j] = s;
    cj[j] = (B[col] - RM[col]) * s + BT[col];
  }
  #pragma unroll
  for (int m = 0; m < 4; ++m){
    int node = node0 + trow * 4 + m;
    if (node < n){
      float4 o; float* op = (float*)&o;
      #pragma unroll
      for (int j = 0; j < 4; ++j){
        float v = lrelu(acc[m][j] * sj[j] + cj[j]);
        if (donan && (v != v)) v = 1e-14f;
        op[j] = v;
      }
      *reinterpret_cast<float4*>(&H[(size_t)node * D + tcol * 4]) = o;
    }
  }
}

// ---------------- candidate MLP: [h_u, h_v, feat] (257) -> 64 -> 64 -> 1 ----------------
__global__ __launch_bounds__(256) void k_mlp(const float* __restrict__ H,
    const int* __restrict__ cu, const int* __restrict__ cv, const float* __restrict__ cf,
    const float* __restrict__ mw0, const float* __restrict__ mb0,
    const float* __restrict__ mw1, const float* __restrict__ mb1,
    const float* __restrict__ mw2, const float* __restrict__ mb2,
    float* __restrict__ y, int C)
{
  int c  = blockIdx.x * 256 + threadIdx.x;
  int cc = min(c, C - 1);                 // avoid divergent control around uniform loads
  const float* hu = &H[(size_t)cu[cc] * D];
  const float* hv = &H[(size_t)cv[cc] * D];

  float a1[64];
  #pragma unroll
  for (int j = 0; j < 64; ++j) a1[j] = mb0[j];

  for (int k4 = 0; k4 < 32; ++k4){
    float4 u4 = *reinterpret_cast<const float4*>(&hu[k4 * 4]);
    const float* up = (const float*)&u4;
    #pragma unroll
    for (int i = 0; i < 4; ++i){
      float ak = up[i]; int k = k4 * 4 + i;
      #pragma unroll
      for (int j = 0; j < 64; ++j) a1[j] = fmaf(ak, mw0[k * 64 + j], a1[j]);
    }
  }
  for (int k4 = 0; k4 < 32; ++k4){
    float4 v4 = *reinterpret_cast<const float4*>(&hv[k4 * 4]);
    const float* vp = (const float*)&v4;
    #pragma unroll
    for (int i = 0; i < 4; ++i){
      float ak = vp[i]; int k = 128 + k4 * 4 + i;
      #pragma unroll
      for (int j = 0; j < 64; ++j) a1[j] = fmaf(ak, mw0[k * 64 + j], a1[j]);
    }
  }
  float cfv = cf[cc];
  #pragma unroll
  for (int j = 0; j < 64; ++j) a1[j] = fmaf(cfv, mw0[256 * 64 + j], a1[j]);

  float a2[64];
  #pragma unroll
  for (int j = 0; j < 64; ++j) a2[j] = mb1[j];
  #pragma unroll
  for (int j = 0; j < 64; ++j){
    float z = lrelu(a1[j]);
    #pragma unroll
    for (int j2 = 0; j2 < 64; ++j2) a2[j2] = fmaf(z, mw1[j * 64 + j2], a2[j2]);
  }

  float yv = mb2[0];
  #pragma unroll
  for (int j = 0; j < 64; ++j) yv = fmaf(lrelu(a2[j]), mw2[j], yv);

  if (c < C) y[c] = yv;
}

// ---------------- softmax over C logits ----------------
__global__ __launch_bounds__(256) void k_red1(const float* __restrict__ y,
                                              float* __restrict__ bmax, float* __restrict__ bsum, int C){
  __shared__ float sm[4];
  __shared__ float ss[4];
  int t = threadIdx.x;
  float m = -3.4e38f;
  for (int i = blockIdx.x * 256 + t; i < C; i += gridDim.x * 256) m = fmaxf(m, y[i]);
  for (int o = 32; o; o >>= 1) m = fmaxf(m, __shfl_xor(m, o));
  if ((t & 63) == 0) sm[t >> 6] = m;
  __syncthreads();
  float bm = fmaxf(fmaxf(sm[0], sm[1]), fmaxf(sm[2], sm[3]));
  float s = 0.f;
  for (int i = blockIdx.x * 256 + t; i < C; i += gridDim.x * 256) s += expf(y[i] - bm);
  for (int o = 32; o; o >>= 1) s += __shfl_xor(s, o);
  if ((t & 63) == 0) ss[t >> 6] = s;
  __syncthreads();
  if (t == 0){ bmax[blockIdx.x] = bm; bsum[blockIdx.x] = ss[0] + ss[1] + ss[2] + ss[3]; }
}

__global__ __launch_bounds__(256) void k_red2(const float* __restrict__ bmax, const float* __restrict__ bsum,
                                              float* __restrict__ g, int nb){
  __shared__ float sm[4];
  __shared__ float ss[4];
  int t = threadIdx.x;
  float m0 = (t < nb) ? bmax[t] : -3.4e38f;
  float m = m0;
  for (int o = 32; o; o >>= 1) m = fmaxf(m, __shfl_xor(m, o));
  if ((t & 63) == 0) sm[t >> 6] = m;
  __syncthreads();
  float gm = fmaxf(fmaxf(sm[0], sm[1]), fmaxf(sm[2], sm[3]));
  float s = (t < nb) ? bsum[t] * expf(m0 - gm) : 0.f;
  for (int o = 32; o; o >>= 1) s += __shfl_xor(s, o);
  if ((t & 63) == 0) ss[t >> 6] = s;
  __syncthreads();
  if (t == 0){ g[0] = gm; g[1] = 1.f / (ss[0] + ss[1] + ss[2] + ss[3]); }
}

__global__ __launch_bounds__(256) void k_red3(const float* __restrict__ y, const float* __restrict__ g,
                                              float* __restrict__ out, int C){
  int i = blockIdx.x * 256 + threadIdx.x;
  if (i < C) out[i] = expf(y[i] - g[0]) * g[1];
}

extern "C" void kernel_launch(void* const* d_in, const int* in_sizes, int n_in,
                              void* d_out, int out_size, void* d_ws, size_t ws_size,
                              hipStream_t stream)
{
  const float* x   = (const float*)d_in[0];
  const int*   src = (const int*)  d_in[1];
  const int*   dst = (const int*)  d_in[2];
  const int*   cu  = (const int*)  d_in[3];
  const int*   cv  = (const int*)  d_in[4];
  const float* cf  = (const float*)d_in[5];
  const float* ws0 = (const float*)d_in[6];
  const float* wn0 = (const float*)d_in[7];
  const float* b0  = (const float*)d_in[8];
  const float* g0  = (const float*)d_in[9];
  const float* be0 = (const float*)d_in[10];
  const float* rm0 = (const float*)d_in[11];
  const float* rv0 = (const float*)d_in[12];
  const float* ws1 = (const float*)d_in[13];
  const float* wn1 = (const float*)d_in[14];
  const float* b1  = (const float*)d_in[15];
  const float* g1  = (const float*)d_in[16];
  const float* be1 = (const float*)d_in[17];
  const float* rm1 = (const float*)d_in[18];
  const float* rv1 = (const float*)d_in[19];
  const float* mw0 = (const float*)d_in[20];
  const float* mb0 = (const float*)d_in[21];
  const float* mw1 = (const float*)d_in[22];
  const float* mb1 = (const float*)d_in[23];
  const float* mw2 = (const float*)d_in[24];
  const float* mb2 = (const float*)d_in[25];

  float* out = (float*)d_out;   // [C] y then [C] softmax

  char* w = (char*)d_ws;
  float* aggn  = (float*)w; w += (size_t)N_NODES * D * 4;
  float* h0    = (float*)w; w += (size_t)N_NODES * D * 4;
  float* h1    = (float*)w; w += (size_t)N_NODES * D * 4;
  int* cnt     = (int*)w;   w += (size_t)N_NODES * 4;
  int* rowptr  = (int*)w;   w += (size_t)(N_NODES + 1) * 4;
  int* cur     = (int*)w;   w += (size_t)N_NODES * 4;
  int* eid     = (int*)w;   w += (size_t)N_EDGES * 4;
  int* bsumI   = (int*)w;   w += 256 * 4;
  float* bmax  = (float*)w; w += 256 * 4;
  float* bsumF = (float*)w; w += 256 * 4;
  float* gred  = (float*)w; w += 2 * 4;

  hipMemsetAsync(cnt, 0, (size_t)N_NODES * 4, stream);
  hipMemsetAsync(cur, 0, (size_t)N_NODES * 4, stream);

  int SB = (N_NODES + 255) / 256;   // 196
  k_hist <<<(N_EDGES + 255) / 256, 256, 0, stream>>>(dst, cnt, N_EDGES);
  k_scan1<<<SB, 256, 0, stream>>>(cnt, rowptr, bsumI, N_NODES);
  k_scan2<<<1, 256, 0, stream>>>(bsumI, rowptr, SB, N_NODES);
  k_scan3<<<SB, 256, 0, stream>>>(rowptr, bsumI, N_NODES);
  k_fill <<<(N_EDGES + 255) / 256, 256, 0, stream>>>(src, dst, rowptr, cur, eid, N_EDGES);

  k_agg <<<(N_NODES + 7) / 8, 256, 0, stream>>>(x, rowptr, eid, aggn, N_NODES);
  k_sage<<<(N_NODES + 31) / 32, 256, 0, stream>>>(x, aggn, ws0, wn0, b0, g0, be0, rm0, rv0, h0, N_NODES, 0);
  k_agg <<<(N_NODES + 7) / 8, 256, 0, stream>>>(h0, rowptr, eid, aggn, N_NODES);
  k_sage<<<(N_NODES + 31) / 32, 256, 0, stream>>>(h0, aggn, ws1, wn1, b1, g1, be1, rm1, rv1, h1, N_NODES, 1);

  k_mlp <<<(N_CAND + 255) / 256, 256, 0, stream>>>(h1, cu, cv, cf, mw0, mb0, mw1, mb1, mw2, mb2, out, N_CAND);

  k_red1<<<256, 256, 0, stream>>>(out, bmax, bsumF, N_CAND);
  k_red2<<<1, 256, 0, stream>>>(bmax, bsumF, gred, 256);
  k_red3<<<(N_CAND + 255) / 256, 256, 0, stream>>>(out, gred, out + N_CAND, N_CAND);
}